// Round 1
// baseline (8788.614 us; speedup 1.0000x reference)
//
#include <hip/hip_runtime.h>
#include <hip/hip_bf16.h>

// ---------------------------------------------------------------------------
// FeatureAggregator: B=8, T=1024, D=2048, E=512, H=8, L=2
// Layout convention: all activations are (M=8192, C) row-major, p = b*T + t.
// ---------------------------------------------------------------------------

#define TM 128
#define TN 128
#define TKC 16

// Weight transform: src (N, K, taps) -> dst [taps][N][K]
__global__ void wtrans_kernel(const float* __restrict__ src, float* __restrict__ dst,
                              int N, int K, int taps)
{
    int total = N * K * taps;
    for (int idx = blockIdx.x * blockDim.x + threadIdx.x; idx < total;
         idx += gridDim.x * blockDim.x) {
        int i   = idx % K;
        int rem = idx / K;
        int o   = rem % N;
        int k   = rem / N;
        dst[idx] = src[((size_t)o * K + i) * (size_t)taps + k];
    }
}

// Generic conv-as-GEMM.  C[p][n] = epilogue( sum_tap sum_i A[p+off_tap][i] * B_tap[n][i] )
// A columns [0,split) come from A1, [split,K) from A2 (concat support); both lda.
// EPI: 0 = +bias, 1 = relu(+bias), 2 = BN(relu(+bias))*wt (optionally +=C),
//      3 = relu(+bias + r1) + r2  (final bottleneck fuse)
template<int EPI>
__global__ __launch_bounds__(256)
void gemm_k(const float* __restrict__ A1, const float* __restrict__ A2, int split, int lda,
            const float* __restrict__ Bw, const float* __restrict__ bias,
            float* __restrict__ C, int ldc,
            int M, int N, int K, int T_,
            int ntaps, int o0, int o1, int o2, int o3, int o4,
            const float* __restrict__ bnp, const float* __restrict__ wtp, int wti, int accum,
            const float* __restrict__ r1, int ldr, const float* __restrict__ r2)
{
    __shared__ float As[TKC][TM + 4];
    __shared__ float Bs[TKC][TN + 4];

    const int tid = threadIdx.x;
    const int m_base = blockIdx.x * TM;
    const int n_base = blockIdx.y * TN;
    const int ty = tid >> 4;      // 0..15  (m micro-row)
    const int tx = tid & 15;      // 0..15  (n micro-col)

    // loader mapping: row-in-tile = tid/2, k-chunk of 8 = (tid&1)*8
    const int lr = tid >> 1;
    const int lk = (tid & 1) * 8;

    const int p  = m_base + lr;           // A row (always < M; M % TM == 0)
    const int bb = p / T_;
    const int tt = p - bb * T_;

    float acc[8][8];
#pragma unroll
    for (int i = 0; i < 8; ++i)
#pragma unroll
        for (int j = 0; j < 8; ++j) acc[i][j] = 0.f;

    for (int tap = 0; tap < ntaps; ++tap) {
        int off;
        switch (tap) { case 0: off = o0; break; case 1: off = o1; break;
                       case 2: off = o2; break; case 3: off = o3; break;
                       default: off = o4; }
        const int tprime = tt + off;
        const bool valid = (tprime >= 0) && (tprime < T_);
        const float* Btap = Bw + (size_t)tap * N * K;
        const float* Brow = Btap + (size_t)(n_base + lr) * K;

        for (int kc = 0; kc < K; kc += TKC) {
            __syncthreads();
            const int c0 = kc + lk;
            float4 av0, av1;
            if (valid) {
                const float* src;
                if (c0 < split) src = A1 + (size_t)(p + off) * lda + c0;
                else            src = A2 + (size_t)(p + off) * lda + (c0 - split);
                av0 = *(const float4*)(src);
                av1 = *(const float4*)(src + 4);
            } else {
                av0 = make_float4(0.f, 0.f, 0.f, 0.f);
                av1 = av0;
            }
            As[lk + 0][lr] = av0.x; As[lk + 1][lr] = av0.y;
            As[lk + 2][lr] = av0.z; As[lk + 3][lr] = av0.w;
            As[lk + 4][lr] = av1.x; As[lk + 5][lr] = av1.y;
            As[lk + 6][lr] = av1.z; As[lk + 7][lr] = av1.w;

            float4 bv0 = *(const float4*)(Brow + c0);
            float4 bv1 = *(const float4*)(Brow + c0 + 4);
            Bs[lk + 0][lr] = bv0.x; Bs[lk + 1][lr] = bv0.y;
            Bs[lk + 2][lr] = bv0.z; Bs[lk + 3][lr] = bv0.w;
            Bs[lk + 4][lr] = bv1.x; Bs[lk + 5][lr] = bv1.y;
            Bs[lk + 6][lr] = bv1.z; Bs[lk + 7][lr] = bv1.w;
            __syncthreads();

#pragma unroll
            for (int kk = 0; kk < TKC; ++kk) {
                float a[8], b[8];
                *(float4*)(a)     = *(const float4*)&As[kk][ty * 8];
                *(float4*)(a + 4) = *(const float4*)&As[kk][ty * 8 + 4];
                *(float4*)(b)     = *(const float4*)&Bs[kk][tx * 8];
                *(float4*)(b + 4) = *(const float4*)&Bs[kk][tx * 8 + 4];
#pragma unroll
                for (int i = 0; i < 8; ++i)
#pragma unroll
                    for (int j = 0; j < 8; ++j)
                        acc[i][j] = fmaf(a[i], b[j], acc[i][j]);
            }
        }
    }

    // epilogue
#pragma unroll
    for (int i = 0; i < 8; ++i) {
        const int row = m_base + ty * 8 + i;
#pragma unroll
        for (int j = 0; j < 8; ++j) {
            const int col = n_base + tx * 8 + j;
            float v = acc[i][j];
            if (bias) v += bias[col];
            if (EPI == 1) v = fmaxf(v, 0.f);
            if (EPI == 2) {
                v = fmaxf(v, 0.f);
                const float g  = bnp[col];
                const float be = bnp[N + col];
                const float mu = bnp[2 * N + col];
                const float va = bnp[3 * N + col];
                v = g * (v - mu) * rsqrtf(va + 1e-5f) + be;
                if (wtp) v *= wtp[wti];
                if (accum) v += C[(size_t)row * ldc + col];
            }
            if (EPI == 3) {
                v += r1[(size_t)row * ldr + col];
                v = fmaxf(v, 0.f) + r2[(size_t)row * 2048 + col];
            }
            C[(size_t)row * ldc + col] = v;
        }
    }
}

// LayerNorm (C=512) in place on x: x = LN(x + t) * g + b, one wave per row.
__global__ __launch_bounds__(256)
void ln_kernel(float* __restrict__ x, const float* __restrict__ t,
               const float* __restrict__ g, const float* __restrict__ b, int M)
{
    const int wave = threadIdx.x >> 6;
    const int lane = threadIdx.x & 63;
    const int row  = blockIdx.x * 4 + wave;
    if (row >= M) return;
    float* xr = x + (size_t)row * 512;
    const float* tr = t + (size_t)row * 512;
    float v[8];
    float s = 0.f, s2 = 0.f;
#pragma unroll
    for (int j = 0; j < 8; ++j) {
        float val = xr[lane * 8 + j] + tr[lane * 8 + j];
        v[j] = val; s += val; s2 += val * val;
    }
#pragma unroll
    for (int d = 1; d < 64; d <<= 1) {
        s  += __shfl_xor(s, d, 64);
        s2 += __shfl_xor(s2, d, 64);
    }
    const float mean = s * (1.f / 512.f);
    const float var  = s2 * (1.f / 512.f) - mean * mean;
    const float rstd = rsqrtf(var + 1e-5f);
#pragma unroll
    for (int j = 0; j < 8; ++j) {
        const int c = lane * 8 + j;
        xr[c] = (v[j] - mean) * rstd * g[c] + b[c];
    }
}

// Flash-style attention: qkv (8192,1536) p=b*T+t; heads H=8, dh=64.
// grid (B*H, T/256), block 256: thread = one q-row.
__global__ __launch_bounds__(256)
void attn_kernel(const float* __restrict__ qkv, float* __restrict__ o)
{
    const int T_ = 1024;
    const int bh = blockIdx.x;
    const int b  = bh >> 3;
    const int h  = bh & 7;
    const int t  = blockIdx.y * 256 + threadIdx.x;

    const float* qrow = qkv + (size_t)(b * T_ + t) * 1536 + h * 64;
    float q[64];
#pragma unroll
    for (int d = 0; d < 64; ++d) q[d] = qrow[d] * 0.125f;

    float O[64];
#pragma unroll
    for (int d = 0; d < 64; ++d) O[d] = 0.f;
    float m = -1e30f, l = 0.f;

    __shared__ float ks[64][64];
    __shared__ float vs[64][64];
    const int r  = threadIdx.x >> 4;          // 0..15
    const int cv = (threadIdx.x & 15) * 4;    // 0..60

    for (int kt = 0; kt < T_ / 64; ++kt) {
        __syncthreads();
#pragma unroll
        for (int pass = 0; pass < 4; ++pass) {
            const int j = r + pass * 16;
            const float* krow = qkv + (size_t)(b * T_ + kt * 64 + j) * 1536 + 512 + h * 64;
            *(float4*)&ks[j][cv] = *(const float4*)&krow[cv];
            *(float4*)&vs[j][cv] = *(const float4*)&krow[512 + cv];
        }
        __syncthreads();
        for (int j = 0; j < 64; ++j) {
            float s = 0.f;
#pragma unroll
            for (int d = 0; d < 64; ++d) s = fmaf(q[d], ks[j][d], s);
            if (s > m) {
                const float c = __expf(m - s);
                m = s; l *= c;
#pragma unroll
                for (int d = 0; d < 64; ++d) O[d] *= c;
            }
            const float p = __expf(s - m);
            l += p;
#pragma unroll
            for (int d = 0; d < 64; ++d) O[d] = fmaf(p, vs[j][d], O[d]);
        }
    }
    const float inv = 1.f / l;
    float* orow = o + (size_t)(b * T_ + t) * 512 + h * 64;
#pragma unroll
    for (int d = 0; d < 64; ++d) orow[d] = O[d] * inv;
}

// ---------------------------------------------------------------------------

extern "C" void kernel_launch(void* const* d_in, const int* in_sizes, int n_in,
                              void* d_out, int out_size, void* d_ws, size_t ws_size,
                              hipStream_t stream)
{
    const float* x       = (const float*)d_in[0];
    const float* wts     = (const float*)d_in[1];
    const float* cw1     = (const float*)d_in[2];
    const float* cb1     = (const float*)d_in[3];
    const float* bn1     = (const float*)d_in[4];
    const float* cw2     = (const float*)d_in[5];
    const float* cb2     = (const float*)d_in[6];
    const float* bn2     = (const float*)d_in[7];
    const float* cw3     = (const float*)d_in[8];
    const float* cb3     = (const float*)d_in[9];
    const float* bn3     = (const float*)d_in[10];
    const float* cw4     = (const float*)d_in[11];
    const float* cb4     = (const float*)d_in[12];
    const float* bn4     = (const float*)d_in[13];
    const float* cw5     = (const float*)d_in[14];
    const float* tcw_in  = (const float*)d_in[15];
    const float* tcb_in  = (const float*)d_in[16];
    const float* t_in_w  = (const float*)d_in[17];
    const float* t_in_b  = (const float*)d_in[18];
    const float* t_out_w = (const float*)d_in[19];
    const float* t_out_b = (const float*)d_in[20];
    const float* ln1_g   = (const float*)d_in[21];
    const float* ln1_b   = (const float*)d_in[22];
    const float* ff_w1   = (const float*)d_in[23];
    const float* ff_b1   = (const float*)d_in[24];
    const float* ff_w2   = (const float*)d_in[25];
    const float* ff_b2   = (const float*)d_in[26];
    const float* ln2_g   = (const float*)d_in[27];
    const float* ln2_b   = (const float*)d_in[28];
    const float* tcw_out = (const float*)d_in[29];
    const float* tcb_out = (const float*)d_in[30];
    const float* cw6     = (const float*)d_in[31];
    const float* bn6     = (const float*)d_in[32];
    const float* bw1     = (const float*)d_in[33];
    const float* bb1     = (const float*)d_in[34];
    const float* bw2     = (const float*)d_in[35];
    const float* bb2     = (const float*)d_in[36];
    const float* bw3     = (const float*)d_in[37];
    const float* bb3     = (const float*)d_in[38];
    float* out = (float*)d_out;

    char* ws = (char*)d_ws;
    float* big  = (float*)(ws);                           // 64 MB: qkv / ff hidden / weight scratch
    float* Wt   = big;
    float* outd = (float*)(ws + (size_t)67108864);        // 16 MB
    float* tmp  = (float*)(ws + (size_t)83886080);        // 16 MB
    float* xtf  = (float*)(ws + (size_t)100663296);       // 16 MB
    float* atn  = (float*)(ws + (size_t)117440512);       // 16 MB
    float* h7   = (float*)(ws + (size_t)134217728);       // 64 MB   (total 192 MB)

    const int M = 8192, T = 1024;
    dim3 blk(256);

    auto wtrans = [&](const float* src, float* dst, int N, int K, int taps) {
        int total = N * K * taps;
        int g = (total + 255) / 256; if (g > 4096) g = 4096;
        wtrans_kernel<<<dim3(g), blk, 0, stream>>>(src, dst, N, K, taps);
    };

    auto gemm = [&](int epi, const float* A1, const float* A2, int split, int lda,
                    const float* Bw, const float* bias, float* C, int ldc,
                    int N, int K, int ntaps, int p0, int p1, int p2, int p3, int p4,
                    const float* bnp, const float* wtp, int wti, int accum,
                    const float* r1, int ldr, const float* r2) {
        dim3 grid(M / TM, N / TN);
        switch (epi) {
        case 0: gemm_k<0><<<grid, blk, 0, stream>>>(A1, A2, split, lda, Bw, bias, C, ldc,
                    M, N, K, T, ntaps, p0, p1, p2, p3, p4, bnp, wtp, wti, accum, r1, ldr, r2); break;
        case 1: gemm_k<1><<<grid, blk, 0, stream>>>(A1, A2, split, lda, Bw, bias, C, ldc,
                    M, N, K, T, ntaps, p0, p1, p2, p3, p4, bnp, wtp, wti, accum, r1, ldr, r2); break;
        case 2: gemm_k<2><<<grid, blk, 0, stream>>>(A1, A2, split, lda, Bw, bias, C, ldc,
                    M, N, K, T, ntaps, p0, p1, p2, p3, p4, bnp, wtp, wti, accum, r1, ldr, r2); break;
        default: gemm_k<3><<<grid, blk, 0, stream>>>(A1, A2, split, lda, Bw, bias, C, ldc,
                    M, N, K, T, ntaps, p0, p1, p2, p3, p4, bnp, wtp, wti, accum, r1, ldr, r2); break;
        }
    };

    // --- multi-dilation branches: out_d = sum_j wts[j] * BN_j(relu(conv_j(x))) ---
    wtrans(cw1, Wt, 512, 2048, 3);
    gemm(2, x, x, 2048, 2048, Wt, cb1, outd, 512, 512, 2048, 3, -1, 0, 1, 0, 0,
         bn1, wts, 0, 0, nullptr, 0, nullptr);
    wtrans(cw2, Wt, 512, 2048, 3);
    gemm(2, x, x, 2048, 2048, Wt, cb2, outd, 512, 512, 2048, 3, -2, 0, 2, 0, 0,
         bn2, wts, 1, 1, nullptr, 0, nullptr);
    wtrans(cw3, Wt, 512, 2048, 3);
    gemm(2, x, x, 2048, 2048, Wt, cb3, outd, 512, 512, 2048, 3, -4, 0, 4, 0, 0,
         bn3, wts, 2, 1, nullptr, 0, nullptr);
    wtrans(cw4, Wt, 512, 2048, 5);
    gemm(2, x, x, 2048, 2048, Wt, cb4, outd, 512, 512, 2048, 5, -8, -4, 0, 4, 8,
         bn4, wts, 3, 1, nullptr, 0, nullptr);

    // --- conv5 (1x1, relu, no bias) -> tmp ---
    gemm(1, x, x, 2048, 2048, cw5, nullptr, tmp, 512, 512, 2048, 1, 0, 0, 0, 0, 0,
         nullptr, nullptr, 0, 0, nullptr, 0, nullptr);
    // --- tcw_in (1x1 + bias) -> xtf ---
    gemm(0, tmp, tmp, 512, 512, tcw_in, tcb_in, xtf, 512, 512, 512, 1, 0, 0, 0, 0, 0,
         nullptr, nullptr, 0, 0, nullptr, 0, nullptr);

    // --- transformer layers ---
    for (int l = 0; l < 2; ++l) {
        gemm(0, xtf, xtf, 512, 512, t_in_w + (size_t)l * 1536 * 512, t_in_b + l * 1536,
             big, 1536, 1536, 512, 1, 0, 0, 0, 0, 0,
             nullptr, nullptr, 0, 0, nullptr, 0, nullptr);
        attn_kernel<<<dim3(64, 4), blk, 0, stream>>>(big, atn);
        gemm(0, atn, atn, 512, 512, t_out_w + (size_t)l * 512 * 512, t_out_b + l * 512,
             tmp, 512, 512, 512, 1, 0, 0, 0, 0, 0,
             nullptr, nullptr, 0, 0, nullptr, 0, nullptr);
        ln_kernel<<<dim3(M / 4), blk, 0, stream>>>(xtf, tmp, ln1_g + l * 512, ln1_b + l * 512, M);
        gemm(1, xtf, xtf, 512, 512, ff_w1 + (size_t)l * 2048 * 512, ff_b1 + l * 2048,
             big, 2048, 2048, 512, 1, 0, 0, 0, 0, 0,
             nullptr, nullptr, 0, 0, nullptr, 0, nullptr);
        gemm(0, big, big, 2048, 2048, ff_w2 + (size_t)l * 512 * 2048, ff_b2 + l * 512,
             tmp, 512, 512, 2048, 1, 0, 0, 0, 0, 0,
             nullptr, nullptr, 0, 0, nullptr, 0, nullptr);
        ln_kernel<<<dim3(M / 4), blk, 0, stream>>>(xtf, tmp, ln2_g + l * 512, ln2_b + l * 512, M);
    }

    // --- tcw_out -> atn (reused) ---
    gemm(0, xtf, xtf, 512, 512, tcw_out, tcb_out, atn, 512, 512, 512, 1, 0, 0, 0, 0, 0,
         nullptr, nullptr, 0, 0, nullptr, 0, nullptr);

    // --- cw6: concat(outd, atn) -> BN6(relu(conv k=3)) -> h7 ---
    wtrans(cw6, Wt, 2048, 1024, 3);
    gemm(2, outd, atn, 512, 512, Wt, nullptr, h7, 2048, 2048, 1024, 3, -1, 0, 1, 0, 0,
         bn6, nullptr, 0, 0, nullptr, 0, nullptr);

    // --- bottleneck ---
    gemm(1, h7, h7, 2048, 2048, bw1, bb1, outd, 512, 512, 2048, 1, 0, 0, 0, 0, 0,
         nullptr, nullptr, 0, 0, nullptr, 0, nullptr);
    wtrans(bw2, Wt, 512, 512, 3);
    gemm(1, outd, outd, 512, 512, Wt, bb2, tmp, 512, 512, 512, 3, -1, 0, 1, 0, 0,
         nullptr, nullptr, 0, 0, nullptr, 0, nullptr);
    // b3 + h7 -> relu -> + x -> d_out
    gemm(3, tmp, tmp, 512, 512, bw3, bb3, out, 2048, 2048, 512, 1, 0, 0, 0, 0, 0,
         nullptr, nullptr, 0, 0, h7, 2048, x);

    (void)in_sizes; (void)n_in; (void)out_size; (void)ws_size;
}

// Round 2
// 2570.293 us; speedup vs baseline: 3.4193x; 3.4193x over previous
//
#include <hip/hip_runtime.h>
#include <hip/hip_bf16.h>

// ---------------------------------------------------------------------------
// FeatureAggregator: B=8, T=1024, D=2048, E=512, H=8, L=2
// Activations: (M=8192, C) row-major, p = b*T + t.  GEMMs: bf16 MFMA.
// ---------------------------------------------------------------------------

typedef __attribute__((ext_vector_type(4))) float f32x4;
typedef __attribute__((ext_vector_type(8))) short short8;
typedef __attribute__((ext_vector_type(8))) unsigned short ushort8;

__device__ __forceinline__ unsigned short f2bu(float f) {
    __hip_bfloat16 h = __float2bfloat16(f);
    return *reinterpret_cast<unsigned short*>(&h);
}

__device__ __forceinline__ void gload16(const void* g, void* l) {
    __builtin_amdgcn_global_load_lds(
        (const __attribute__((address_space(1))) unsigned int*)g,
        (__attribute__((address_space(3))) unsigned int*)l, 16, 0, 0);
}

// fp32 -> bf16 cast, 8 elems/thread/iter
__global__ void cast_kernel(const float* __restrict__ in, unsigned short* __restrict__ out, int n8)
{
    for (int i = blockIdx.x * blockDim.x + threadIdx.x; i < n8; i += gridDim.x * blockDim.x) {
        const float4* p = (const float4*)in + (size_t)i * 2;
        float4 a = p[0], b = p[1];
        ushort8 o;
        o[0] = f2bu(a.x); o[1] = f2bu(a.y); o[2] = f2bu(a.z); o[3] = f2bu(a.w);
        o[4] = f2bu(b.x); o[5] = f2bu(b.y); o[6] = f2bu(b.z); o[7] = f2bu(b.w);
        *(ushort8*)(out + (size_t)i * 8) = o;
    }
}

// Weight transform: src (N, K, taps) fp32 -> dst [taps][N][K] bf16
__global__ void wtrans_kernel(const float* __restrict__ src, __hip_bfloat16* __restrict__ dst,
                              int N, int K, int taps)
{
    int total = N * K * taps;
    for (int idx = blockIdx.x * blockDim.x + threadIdx.x; idx < total;
         idx += gridDim.x * blockDim.x) {
        int i   = idx % K;
        int rem = idx / K;
        int o   = rem % N;
        int k   = rem / N;
        dst[idx] = __float2bfloat16(src[((size_t)o * K + i) * (size_t)taps + k]);
    }
}

// ---------------------------------------------------------------------------
// bf16 MFMA conv-as-GEMM.  C[p][n] = epi( sum_tap sum_i A[p+off][i] * B_tap[n][i] )
// A cols [0,split) from A1 (lda1), rest from A2 (lda2).  Tile BM_ x 128, BK=32.
// 4 waves in 2x2; wave tile (BM_/2) x 64; 16x16x32 MFMA fragments.
// EPI: 0=+bias, 1=relu(+bias), 2=BN(relu(+bias))*wt (opt +=Cf), 3=relu(+bias+r1)+r2
// ---------------------------------------------------------------------------
template<int BM_, int EPI>
__global__ __launch_bounds__(256)
void mgemm(const __hip_bfloat16* __restrict__ A1, const __hip_bfloat16* __restrict__ A2,
           int split, int lda1, int lda2,
           const __hip_bfloat16* __restrict__ Bw, const float* __restrict__ bias,
           float* __restrict__ Cf, __hip_bfloat16* __restrict__ Cb, int ldc,
           int N, int K, int T_,
           int ntaps, int o0, int o1, int o2, int o3, int o4,
           const float* __restrict__ bnp, const float* __restrict__ wtp, int wti, int accum,
           const float* __restrict__ r1, int ldr, const float* __restrict__ r2,
           const __hip_bfloat16* __restrict__ zb)
{
    constexpr int MREP   = BM_ / 32;   // fragments per wave in M
    constexpr int A_INST = BM_ / 64;   // global_load_lds insts per thread for A

    __shared__ __align__(16) short As[BM_ * 32];
    __shared__ __align__(16) short Bs[128 * 32];

    const int tid  = threadIdx.x;
    const int w    = tid >> 6;
    const int lane = tid & 63;
    const int wr   = w >> 1, wc = w & 1;
    const int m_base = blockIdx.x * BM_;
    const int n_base = blockIdx.y * 128;
    const int lr = lane >> 2;          // 0..15 row within 16-row stripe
    const int lc = (lane & 3) * 8;     // bf16 col 0,8,16,24

    f32x4 acc[MREP][4];
#pragma unroll
    for (int m = 0; m < MREP; ++m)
#pragma unroll
        for (int n = 0; n < 4; ++n) acc[m][n] = (f32x4){0.f, 0.f, 0.f, 0.f};

    for (int tap = 0; tap < ntaps; ++tap) {
        int off;
        switch (tap) { case 0: off = o0; break; case 1: off = o1; break;
                       case 2: off = o2; break; case 3: off = o3; break;
                       default: off = o4; }

        for (int kc = 0; kc < K; kc += 32) {
            __syncthreads();
            // ---- stage B tile (128 x 32) ----
#pragma unroll
            for (int i = 0; i < 2; ++i) {
                const int r = i * 64 + w * 16 + lr;
                const void* src = (const void*)(Bw + ((size_t)tap * N + n_base + r) * K + kc + lc);
                gload16(src, (void*)&Bs[(i * 64 + w * 16) * 32]);
            }
            // ---- stage A tile (BM_ x 32) with conv-offset masking ----
#pragma unroll
            for (int i = 0; i < A_INST; ++i) {
                const int r  = i * 64 + w * 16 + lr;
                const int p  = m_base + r;
                const int tt = p & (T_ - 1);
                const int tp = tt + off;
                const void* src;
                if ((unsigned)tp < (unsigned)T_) {
                    if (kc < split)
                        src = (const void*)(A1 + (size_t)(p + off) * lda1 + kc + lc);
                    else
                        src = (const void*)(A2 + (size_t)(p + off) * lda2 + (kc - split) + lc);
                } else {
                    src = (const void*)zb;
                }
                gload16(src, (void*)&As[(i * 64 + w * 16) * 32]);
            }
            __syncthreads();

            // ---- compute ----
            short8 a[MREP], b[4];
#pragma unroll
            for (int m = 0; m < MREP; ++m)
                a[m] = *(const short8*)&As[(wr * (BM_ / 2) + m * 16 + (lane & 15)) * 32 + (lane >> 4) * 8];
#pragma unroll
            for (int n = 0; n < 4; ++n)
                b[n] = *(const short8*)&Bs[(wc * 64 + n * 16 + (lane & 15)) * 32 + (lane >> 4) * 8];
#pragma unroll
            for (int m = 0; m < MREP; ++m)
#pragma unroll
                for (int n = 0; n < 4; ++n)
                    acc[m][n] = __builtin_amdgcn_mfma_f32_16x16x32_bf16(a[m], b[n], acc[m][n], 0, 0, 0);
        }
    }

    // ---- epilogue:  C row = (lane>>4)*4 + j, col = lane&15 ----
#pragma unroll
    for (int m = 0; m < MREP; ++m) {
#pragma unroll
        for (int n = 0; n < 4; ++n) {
#pragma unroll
            for (int j = 0; j < 4; ++j) {
                const int row = m_base + wr * (BM_ / 2) + m * 16 + (lane >> 4) * 4 + j;
                const int col = n_base + wc * 64 + n * 16 + (lane & 15);
                float v = acc[m][n][j];
                if (bias) v += bias[col];
                const size_t idx = (size_t)row * ldc + col;
                if (EPI == 1) v = fmaxf(v, 0.f);
                if (EPI == 2) {
                    v = fmaxf(v, 0.f);
                    const float g  = bnp[col];
                    const float be = bnp[N + col];
                    const float mu = bnp[2 * N + col];
                    const float va = bnp[3 * N + col];
                    v = g * (v - mu) * rsqrtf(va + 1e-5f) + be;
                    if (wtp) v *= wtp[wti];
                    if (accum) v += Cf[idx];
                }
                if (EPI == 3) {
                    v += r1[(size_t)row * ldr + col];
                    v = fmaxf(v, 0.f) + r2[(size_t)row * 2048 + col];
                    Cf[idx] = v;
                } else {
                    if (Cf) Cf[idx] = v;
                    if (Cb) Cb[idx] = __float2bfloat16(v);
                }
            }
        }
    }
}

// LayerNorm (C=512): x = LN(x + t) * g + b; also writes bf16 copy.
__global__ __launch_bounds__(256)
void ln_kernel(float* __restrict__ x, const float* __restrict__ t,
               const float* __restrict__ g, const float* __restrict__ b,
               __hip_bfloat16* __restrict__ xb, int M)
{
    const int wave = threadIdx.x >> 6;
    const int lane = threadIdx.x & 63;
    const int row  = blockIdx.x * 4 + wave;
    if (row >= M) return;
    float* xr = x + (size_t)row * 512;
    const float* tr = t + (size_t)row * 512;
    float v[8];
    float s = 0.f, s2 = 0.f;
#pragma unroll
    for (int j = 0; j < 8; ++j) {
        float val = xr[lane * 8 + j] + tr[lane * 8 + j];
        v[j] = val; s += val; s2 += val * val;
    }
#pragma unroll
    for (int d = 1; d < 64; d <<= 1) {
        s  += __shfl_xor(s, d, 64);
        s2 += __shfl_xor(s2, d, 64);
    }
    const float mean = s * (1.f / 512.f);
    const float var  = s2 * (1.f / 512.f) - mean * mean;
    const float rstd = rsqrtf(var + 1e-5f);
#pragma unroll
    for (int j = 0; j < 8; ++j) {
        const int c = lane * 8 + j;
        const float o = (v[j] - mean) * rstd * g[c] + b[c];
        xr[c] = o;
        xb[(size_t)row * 512 + c] = __float2bfloat16(o);
    }
}

// Flash-style attention, fp32 in (qkv 8192x1536), bf16 out.
__global__ __launch_bounds__(256)
void attn_kernel(const float* __restrict__ qkv, __hip_bfloat16* __restrict__ o)
{
    const int T_ = 1024;
    const int bh = blockIdx.x;
    const int b  = bh >> 3;
    const int h  = bh & 7;
    const int t  = blockIdx.y * 256 + threadIdx.x;

    const float* qrow = qkv + (size_t)(b * T_ + t) * 1536 + h * 64;
    float q[64];
#pragma unroll
    for (int d = 0; d < 64; ++d) q[d] = qrow[d] * 0.125f;

    float O[64];
#pragma unroll
    for (int d = 0; d < 64; ++d) O[d] = 0.f;
    float m = -1e30f, l = 0.f;

    __shared__ float ks[64][64];
    __shared__ float vs[64][64];
    const int r  = threadIdx.x >> 4;
    const int cv = (threadIdx.x & 15) * 4;

    for (int kt = 0; kt < T_ / 64; ++kt) {
        __syncthreads();
#pragma unroll
        for (int pass = 0; pass < 4; ++pass) {
            const int j = r + pass * 16;
            const float* krow = qkv + (size_t)(b * T_ + kt * 64 + j) * 1536 + 512 + h * 64;
            *(float4*)&ks[j][cv] = *(const float4*)&krow[cv];
            *(float4*)&vs[j][cv] = *(const float4*)&krow[512 + cv];
        }
        __syncthreads();
        for (int j = 0; j < 64; ++j) {
            float s = 0.f;
#pragma unroll
            for (int d = 0; d < 64; ++d) s = fmaf(q[d], ks[j][d], s);
            if (s > m) {
                const float c = __expf(m - s);
                m = s; l *= c;
#pragma unroll
                for (int d = 0; d < 64; ++d) O[d] *= c;
            }
            const float p = __expf(s - m);
            l += p;
#pragma unroll
            for (int d = 0; d < 64; ++d) O[d] = fmaf(p, vs[j][d], O[d]);
        }
    }
    const float inv = 1.f / l;
    __hip_bfloat16* orow = o + (size_t)(b * T_ + t) * 512 + h * 64;
#pragma unroll
    for (int d = 0; d < 64; ++d) orow[d] = __float2bfloat16(O[d] * inv);
}

// ---------------------------------------------------------------------------

extern "C" void kernel_launch(void* const* d_in, const int* in_sizes, int n_in,
                              void* d_out, int out_size, void* d_ws, size_t ws_size,
                              hipStream_t stream)
{
    const float* x       = (const float*)d_in[0];
    const float* wts     = (const float*)d_in[1];
    const float* cw1     = (const float*)d_in[2];
    const float* cb1     = (const float*)d_in[3];
    const float* bn1     = (const float*)d_in[4];
    const float* cw2     = (const float*)d_in[5];
    const float* cb2     = (const float*)d_in[6];
    const float* bn2     = (const float*)d_in[7];
    const float* cw3     = (const float*)d_in[8];
    const float* cb3     = (const float*)d_in[9];
    const float* bn3     = (const float*)d_in[10];
    const float* cw4     = (const float*)d_in[11];
    const float* cb4     = (const float*)d_in[12];
    const float* bn4     = (const float*)d_in[13];
    const float* cw5     = (const float*)d_in[14];
    const float* tcw_in  = (const float*)d_in[15];
    const float* tcb_in  = (const float*)d_in[16];
    const float* t_in_w  = (const float*)d_in[17];
    const float* t_in_b  = (const float*)d_in[18];
    const float* t_out_w = (const float*)d_in[19];
    const float* t_out_b = (const float*)d_in[20];
    const float* ln1_g   = (const float*)d_in[21];
    const float* ln1_b   = (const float*)d_in[22];
    const float* ff_w1   = (const float*)d_in[23];
    const float* ff_b1   = (const float*)d_in[24];
    const float* ff_w2   = (const float*)d_in[25];
    const float* ff_b2   = (const float*)d_in[26];
    const float* ln2_g   = (const float*)d_in[27];
    const float* ln2_b   = (const float*)d_in[28];
    const float* tcw_out = (const float*)d_in[29];
    const float* tcb_out = (const float*)d_in[30];
    const float* cw6     = (const float*)d_in[31];
    const float* bn6     = (const float*)d_in[32];
    const float* bw1     = (const float*)d_in[33];
    const float* bb1     = (const float*)d_in[34];
    const float* bw2     = (const float*)d_in[35];
    const float* bb2     = (const float*)d_in[36];
    const float* bw3     = (const float*)d_in[37];
    const float* bb3     = (const float*)d_in[38];
    float* out = (float*)d_out;

    const size_t MBy = 1048576;
    char* ws = (char*)d_ws;
    __hip_bfloat16* xb    = (__hip_bfloat16*)(ws);                 // 32MB, later wtf/h7
    float*          bigq  = (float*)(ws + 32 * MBy);               // 48MB qkv fp32 (early: wte)
    __hip_bfloat16* wte   = (__hip_bfloat16*)(ws + 32 * MBy);      // early weights (alias bigq)
    __hip_bfloat16* wtf   = (__hip_bfloat16*)(ws);                 // transformer weights (alias xb)
    float*          h7    = (float*)(ws);                          // 64MB (alias xb+bigq head)
    __hip_bfloat16* wt6   = (__hip_bfloat16*)(ws + 64 * MBy);      // 12MB cw6 weights
    __hip_bfloat16* bigb  = (__hip_bfloat16*)(ws + 80 * MBy);      // 32MB ff hidden bf16
    __hip_bfloat16* h7b   = (__hip_bfloat16*)(ws + 80 * MBy);      // alias bigb (after ff done)
    float*          outd  = (float*)(ws + 112 * MBy);              // 16MB
    __hip_bfloat16* outdb = (__hip_bfloat16*)(ws + 128 * MBy);     // 8MB, later u1b
    float*          tmp   = (float*)(ws + 136 * MBy);              // 16MB fp32 LN input
    __hip_bfloat16* zb    = (__hip_bfloat16*)(ws + 136 * MBy);     // 4KB zero row (alias tmp head)
    __hip_bfloat16* wtb1  = (__hip_bfloat16*)(ws + 137 * MBy);
    __hip_bfloat16* wtb2  = (__hip_bfloat16*)(ws + 140 * MBy);
    __hip_bfloat16* wtb3  = (__hip_bfloat16*)(ws + 144 * MBy);
    __hip_bfloat16* tmpb  = (__hip_bfloat16*)(ws + 152 * MBy);     // 8MB conv5 out, later u2b
    float*          xtf   = (float*)(ws + 160 * MBy);              // 16MB
    __hip_bfloat16* xtfb  = (__hip_bfloat16*)(ws + 176 * MBy);     // 8MB
    __hip_bfloat16* atnb  = (__hip_bfloat16*)(ws + 184 * MBy);     // 8MB

    const int M = 8192;
    dim3 blk(256);

    auto wtrans = [&](const float* src, __hip_bfloat16* dst, int N, int K, int taps) {
        int total = N * K * taps;
        int g = (total + 255) / 256; if (g > 4096) g = 4096;
        wtrans_kernel<<<dim3(g), blk, 0, stream>>>(src, dst, N, K, taps);
    };

    auto mg = [&](int bm, int epi, const __hip_bfloat16* A1, const __hip_bfloat16* A2,
                  int split, int lda1, int lda2,
                  const __hip_bfloat16* Bw, const float* bias,
                  float* Cf, __hip_bfloat16* Cb, int ldc, int N, int K,
                  int ntaps, int p0, int p1, int p2, int p3, int p4,
                  const float* bnp, const float* wtp, int wti, int accum,
                  const float* r1, int ldr, const float* r2) {
        dim3 grid(M / bm, N / 128);
#define LAU(BMV, EPIV) mgemm<BMV, EPIV><<<grid, blk, 0, stream>>>(A1, A2, split, lda1, lda2, \
        Bw, bias, Cf, Cb, ldc, N, K, 1024, ntaps, p0, p1, p2, p3, p4, bnp, wtp, wti, accum, r1, ldr, r2, zb)
        if (bm == 64) {
            switch (epi) { case 0: LAU(64, 0); break; case 1: LAU(64, 1); break;
                           case 2: LAU(64, 2); break; default: LAU(64, 3); }
        } else {
            switch (epi) { case 0: LAU(128, 0); break; case 1: LAU(128, 1); break;
                           case 2: LAU(128, 2); break; default: LAU(128, 3); }
        }
#undef LAU
    };

    // zero scratch row for conv-boundary masking
    hipMemsetAsync(zb, 0, 4096, stream);
    // x -> bf16
    cast_kernel<<<dim3(2048), blk, 0, stream>>>(x, (unsigned short*)xb, M * 2048 / 8);

    // --- multi-dilation branches ---
    wtrans(cw1, wte, 512, 2048, 3);
    mg(64, 2, xb, xb, 4096, 2048, 2048, wte, cb1, outd, nullptr, 512, 512, 2048,
       3, -1, 0, 1, 0, 0, bn1, wts, 0, 0, nullptr, 0, nullptr);
    wtrans(cw2, wte, 512, 2048, 3);
    mg(64, 2, xb, xb, 4096, 2048, 2048, wte, cb2, outd, nullptr, 512, 512, 2048,
       3, -2, 0, 2, 0, 0, bn2, wts, 1, 1, nullptr, 0, nullptr);
    wtrans(cw3, wte, 512, 2048, 3);
    mg(64, 2, xb, xb, 4096, 2048, 2048, wte, cb3, outd, nullptr, 512, 512, 2048,
       3, -4, 0, 4, 0, 0, bn3, wts, 2, 1, nullptr, 0, nullptr);
    wtrans(cw4, wte, 512, 2048, 5);
    mg(64, 2, xb, xb, 4096, 2048, 2048, wte, cb4, outd, outdb, 512, 512, 2048,
       5, -8, -4, 0, 4, 8, bn4, wts, 3, 1, nullptr, 0, nullptr);

    // --- conv5 (relu, no bias) -> tmpb ---
    wtrans(cw5, wte, 512, 2048, 1);
    mg(64, 1, xb, xb, 4096, 2048, 2048, wte, nullptr, nullptr, tmpb, 512, 512, 2048,
       1, 0, 0, 0, 0, 0, nullptr, nullptr, 0, 0, nullptr, 0, nullptr);

    // --- tcw_in -> xtf (+xtfb) ---   (xb region now dead -> wtf)
    wtrans(tcw_in, wtf, 512, 512, 1);
    mg(64, 0, tmpb, tmpb, 4096, 512, 512, wtf, tcb_in, xtf, xtfb, 512, 512, 512,
       1, 0, 0, 0, 0, 0, nullptr, nullptr, 0, 0, nullptr, 0, nullptr);

    // --- transformer layers ---
    for (int l = 0; l < 2; ++l) {
        wtrans(t_in_w + (size_t)l * 1536 * 512, wtf, 1536, 512, 1);
        mg(128, 0, xtfb, xtfb, 4096, 512, 512, wtf, t_in_b + l * 1536, bigq, nullptr, 1536,
           1536, 512, 1, 0, 0, 0, 0, 0, nullptr, nullptr, 0, 0, nullptr, 0, nullptr);
        attn_kernel<<<dim3(64, 4), blk, 0, stream>>>(bigq, atnb);
        wtrans(t_out_w + (size_t)l * 512 * 512, wtf, 512, 512, 1);
        mg(64, 0, atnb, atnb, 4096, 512, 512, wtf, t_out_b + l * 512, tmp, nullptr, 512,
           512, 512, 1, 0, 0, 0, 0, 0, nullptr, nullptr, 0, 0, nullptr, 0, nullptr);
        ln_kernel<<<dim3(M / 4), blk, 0, stream>>>(xtf, tmp, ln1_g + l * 512, ln1_b + l * 512, xtfb, M);
        wtrans(ff_w1 + (size_t)l * 2048 * 512, wtf, 2048, 512, 1);
        mg(128, 1, xtfb, xtfb, 4096, 512, 512, wtf, ff_b1 + l * 2048, nullptr, bigb, 2048,
           2048, 512, 1, 0, 0, 0, 0, 0, nullptr, nullptr, 0, 0, nullptr, 0, nullptr);
        wtrans(ff_w2 + (size_t)l * 512 * 2048, wtf, 512, 2048, 1);
        mg(64, 0, bigb, bigb, 4096, 2048, 2048, wtf, ff_b2 + l * 512, tmp, nullptr, 512,
           512, 2048, 1, 0, 0, 0, 0, 0, nullptr, nullptr, 0, 0, nullptr, 0, nullptr);
        ln_kernel<<<dim3(M / 4), blk, 0, stream>>>(xtf, tmp, ln2_g + l * 512, ln2_b + l * 512, xtfb, M);
    }

    // --- tcw_out -> atnb (bf16 only) ---
    wtrans(tcw_out, wtf, 512, 512, 1);
    mg(64, 0, xtfb, xtfb, 4096, 512, 512, wtf, tcb_out, nullptr, atnb, 512, 512, 512,
       1, 0, 0, 0, 0, 0, nullptr, nullptr, 0, 0, nullptr, 0, nullptr);

    // --- cw6: concat(outdb, atnb) k=3 -> BN6 -> h7 (fp32 + bf16) ---
    hipMemsetAsync(zb, 0, 4096, stream);   // tmp region was clobbered; re-zero mask row
    wtrans(cw6, wt6, 2048, 1024, 3);
    mg(128, 2, outdb, atnb, 512, 512, 512, wt6, nullptr, h7, h7b, 2048, 2048, 1024,
       3, -1, 0, 1, 0, 0, bn6, nullptr, 0, 0, nullptr, 0, nullptr);

    // --- bottleneck ---
    wtrans(bw1, wtb1, 512, 2048, 1);
    mg(64, 1, h7b, h7b, 4096, 2048, 2048, wtb1, bb1, nullptr, outdb, 512, 512, 2048,
       1, 0, 0, 0, 0, 0, nullptr, nullptr, 0, 0, nullptr, 0, nullptr);
    wtrans(bw2, wtb2, 512, 512, 3);
    mg(64, 1, outdb, outdb, 4096, 512, 512, wtb2, bb2, nullptr, tmpb, 512, 512, 512,
       3, -1, 0, 1, 0, 0, nullptr, nullptr, 0, 0, nullptr, 0, nullptr);
    wtrans(bw3, wtb3, 2048, 512, 1);
    mg(128, 3, tmpb, tmpb, 4096, 512, 512, wtb3, bb3, out, nullptr, 2048, 2048, 512,
       1, 0, 0, 0, 0, 0, nullptr, nullptr, 0, 0, h7, 2048, x);

    (void)in_sizes; (void)n_in; (void)out_size; (void)ws_size;
}

// Round 3
// 1544.557 us; speedup vs baseline: 5.6901x; 1.6641x over previous
//
#include <hip/hip_runtime.h>
#include <hip/hip_bf16.h>

// ---------------------------------------------------------------------------
// FeatureAggregator: B=8, T=1024, D=2048, E=512, H=8, L=2
// Activations: (M=8192, C) row-major, p = b*T + t.  GEMMs + attention: bf16 MFMA.
// ---------------------------------------------------------------------------

typedef __attribute__((ext_vector_type(4))) float f32x4;
typedef __attribute__((ext_vector_type(8))) short short8;
typedef __attribute__((ext_vector_type(8))) unsigned short ushort8;

__device__ __forceinline__ unsigned short f2bu(float f) {
    __hip_bfloat16 h = __float2bfloat16(f);
    return *reinterpret_cast<unsigned short*>(&h);
}

__device__ __forceinline__ void gload16(const void* g, void* l) {
    __builtin_amdgcn_global_load_lds(
        (const __attribute__((address_space(1))) unsigned int*)g,
        (__attribute__((address_space(3))) unsigned int*)l, 16, 0, 0);
}

// fp32 -> bf16 cast, 8 elems/thread/iter
__global__ void cast_kernel(const float* __restrict__ in, unsigned short* __restrict__ out, int n8)
{
    for (int i = blockIdx.x * blockDim.x + threadIdx.x; i < n8; i += gridDim.x * blockDim.x) {
        const float4* p = (const float4*)in + (size_t)i * 2;
        float4 a = p[0], b = p[1];
        ushort8 o;
        o[0] = f2bu(a.x); o[1] = f2bu(a.y); o[2] = f2bu(a.z); o[3] = f2bu(a.w);
        o[4] = f2bu(b.x); o[5] = f2bu(b.y); o[6] = f2bu(b.z); o[7] = f2bu(b.w);
        *(ushort8*)(out + (size_t)i * 8) = o;
    }
}

// Weight transform: src (N, K, taps) fp32 -> dst [taps][N][K] bf16
__global__ void wtrans_kernel(const float* __restrict__ src, __hip_bfloat16* __restrict__ dst,
                              int N, int K, int taps)
{
    int total = N * K * taps;
    for (int idx = blockIdx.x * blockDim.x + threadIdx.x; idx < total;
         idx += gridDim.x * blockDim.x) {
        int i   = idx % K;
        int rem = idx / K;
        int o   = rem % N;
        int k   = rem / N;
        dst[idx] = __float2bfloat16(src[((size_t)o * K + i) * (size_t)taps + k]);
    }
}

// ---------------------------------------------------------------------------
// bf16 MFMA conv-as-GEMM (unchanged from R2).
// ---------------------------------------------------------------------------
template<int BM_, int EPI>
__global__ __launch_bounds__(256)
void mgemm(const __hip_bfloat16* __restrict__ A1, const __hip_bfloat16* __restrict__ A2,
           int split, int lda1, int lda2,
           const __hip_bfloat16* __restrict__ Bw, const float* __restrict__ bias,
           float* __restrict__ Cf, __hip_bfloat16* __restrict__ Cb, int ldc,
           int N, int K, int T_,
           int ntaps, int o0, int o1, int o2, int o3, int o4,
           const float* __restrict__ bnp, const float* __restrict__ wtp, int wti, int accum,
           const float* __restrict__ r1, int ldr, const float* __restrict__ r2,
           const __hip_bfloat16* __restrict__ zb)
{
    constexpr int MREP   = BM_ / 32;
    constexpr int A_INST = BM_ / 64;

    __shared__ __align__(16) short As[BM_ * 32];
    __shared__ __align__(16) short Bs[128 * 32];

    const int tid  = threadIdx.x;
    const int w    = tid >> 6;
    const int lane = tid & 63;
    const int wr   = w >> 1, wc = w & 1;
    const int m_base = blockIdx.x * BM_;
    const int n_base = blockIdx.y * 128;
    const int lr = lane >> 2;
    const int lc = (lane & 3) * 8;

    f32x4 acc[MREP][4];
#pragma unroll
    for (int m = 0; m < MREP; ++m)
#pragma unroll
        for (int n = 0; n < 4; ++n) acc[m][n] = (f32x4){0.f, 0.f, 0.f, 0.f};

    for (int tap = 0; tap < ntaps; ++tap) {
        int off;
        switch (tap) { case 0: off = o0; break; case 1: off = o1; break;
                       case 2: off = o2; break; case 3: off = o3; break;
                       default: off = o4; }

        for (int kc = 0; kc < K; kc += 32) {
            __syncthreads();
#pragma unroll
            for (int i = 0; i < 2; ++i) {
                const int r = i * 64 + w * 16 + lr;
                const void* src = (const void*)(Bw + ((size_t)tap * N + n_base + r) * K + kc + lc);
                gload16(src, (void*)&Bs[(i * 64 + w * 16) * 32]);
            }
#pragma unroll
            for (int i = 0; i < A_INST; ++i) {
                const int r  = i * 64 + w * 16 + lr;
                const int p  = m_base + r;
                const int tt = p & (T_ - 1);
                const int tp = tt + off;
                const void* src;
                if ((unsigned)tp < (unsigned)T_) {
                    if (kc < split)
                        src = (const void*)(A1 + (size_t)(p + off) * lda1 + kc + lc);
                    else
                        src = (const void*)(A2 + (size_t)(p + off) * lda2 + (kc - split) + lc);
                } else {
                    src = (const void*)zb;
                }
                gload16(src, (void*)&As[(i * 64 + w * 16) * 32]);
            }
            __syncthreads();

            short8 a[MREP], b[4];
#pragma unroll
            for (int m = 0; m < MREP; ++m)
                a[m] = *(const short8*)&As[(wr * (BM_ / 2) + m * 16 + (lane & 15)) * 32 + (lane >> 4) * 8];
#pragma unroll
            for (int n = 0; n < 4; ++n)
                b[n] = *(const short8*)&Bs[(wc * 64 + n * 16 + (lane & 15)) * 32 + (lane >> 4) * 8];
#pragma unroll
            for (int m = 0; m < MREP; ++m)
#pragma unroll
                for (int n = 0; n < 4; ++n)
                    acc[m][n] = __builtin_amdgcn_mfma_f32_16x16x32_bf16(a[m], b[n], acc[m][n], 0, 0, 0);
        }
    }

#pragma unroll
    for (int m = 0; m < MREP; ++m) {
#pragma unroll
        for (int n = 0; n < 4; ++n) {
#pragma unroll
            for (int j = 0; j < 4; ++j) {
                const int row = m_base + wr * (BM_ / 2) + m * 16 + (lane >> 4) * 4 + j;
                const int col = n_base + wc * 64 + n * 16 + (lane & 15);
                float v = acc[m][n][j];
                if (bias) v += bias[col];
                const size_t idx = (size_t)row * ldc + col;
                if (EPI == 1) v = fmaxf(v, 0.f);
                if (EPI == 2) {
                    v = fmaxf(v, 0.f);
                    const float g  = bnp[col];
                    const float be = bnp[N + col];
                    const float mu = bnp[2 * N + col];
                    const float va = bnp[3 * N + col];
                    v = g * (v - mu) * rsqrtf(va + 1e-5f) + be;
                    if (wtp) v *= wtp[wti];
                    if (accum) v += Cf[idx];
                }
                if (EPI == 3) {
                    v += r1[(size_t)row * ldr + col];
                    v = fmaxf(v, 0.f) + r2[(size_t)row * 2048 + col];
                    Cf[idx] = v;
                } else {
                    if (Cf) Cf[idx] = v;
                    if (Cb) Cb[idx] = __float2bfloat16(v);
                }
            }
        }
    }
}

// LayerNorm (C=512): x = LN(x + t) * g + b; also writes bf16 copy.
__global__ __launch_bounds__(256)
void ln_kernel(float* __restrict__ x, const float* __restrict__ t,
               const float* __restrict__ g, const float* __restrict__ b,
               __hip_bfloat16* __restrict__ xb, int M)
{
    const int wave = threadIdx.x >> 6;
    const int lane = threadIdx.x & 63;
    const int row  = blockIdx.x * 4 + wave;
    if (row >= M) return;
    float* xr = x + (size_t)row * 512;
    const float* tr = t + (size_t)row * 512;
    float v[8];
    float s = 0.f, s2 = 0.f;
#pragma unroll
    for (int j = 0; j < 8; ++j) {
        float val = xr[lane * 8 + j] + tr[lane * 8 + j];
        v[j] = val; s += val; s2 += val * val;
    }
#pragma unroll
    for (int d = 1; d < 64; d <<= 1) {
        s  += __shfl_xor(s, d, 64);
        s2 += __shfl_xor(s2, d, 64);
    }
    const float mean = s * (1.f / 512.f);
    const float var  = s2 * (1.f / 512.f) - mean * mean;
    const float rstd = rsqrtf(var + 1e-5f);
#pragma unroll
    for (int j = 0; j < 8; ++j) {
        const int c = lane * 8 + j;
        const float o = (v[j] - mean) * rstd * g[c] + b[c];
        xr[c] = o;
        xb[(size_t)row * 512 + c] = __float2bfloat16(o);
    }
}

// ---------------------------------------------------------------------------
// MFMA flash attention (bf16 in/out).  qkv: (8192,1536) bf16 [Q|K|V], H=8 dh=64.
// Grid (B*H=64, T/128=8), 256 thr (4 waves); wave = 32 q-rows; KV tile 64.
// S = Q K^T via 16x16x32 MFMA; online softmax in C-fragments; P via wave-
// private swizzled LDS; PV with V^T staged in swizzled LDS.
// ---------------------------------------------------------------------------
__global__ __launch_bounds__(256)
void mattn(const __hip_bfloat16* __restrict__ qkv, __hip_bfloat16* __restrict__ o)
{
    __shared__ __align__(16) short Ks[4096];   // 64 keys x 64 d  (XOR swz)
    __shared__ __align__(16) short Vt[4096];   // 64 d   x 64 key (XOR swz)
    __shared__ __align__(16) short Pl[8192];   // 4 waves x 32 q x 64 key (XOR swz)

    const int tid  = threadIdx.x;
    const int w    = tid >> 6;
    const int lane = tid & 63;
    const int g    = lane >> 4;      // 0..3
    const int li   = lane & 15;      // 0..15
    const int b    = blockIdx.x >> 3;
    const int h    = blockIdx.x & 7;
    const int qb   = blockIdx.y * 128 + w * 32;

    const short* qkvs = (const short*)qkv;

    // Q A-fragments: row = li, k-cols = ks*32 + g*8 .. +8
    short8 qf[2][2];
#pragma unroll
    for (int m = 0; m < 2; ++m)
#pragma unroll
        for (int ks = 0; ks < 2; ++ks)
            qf[m][ks] = *(const short8*)(qkvs +
                (size_t)(b * 1024 + qb + m * 16 + li) * 1536 + h * 64 + ks * 32 + g * 8);

    f32x4 Oa[2][4];
    float mr[2][4], lr[2][4];
#pragma unroll
    for (int m = 0; m < 2; ++m)
#pragma unroll
        for (int j = 0; j < 4; ++j) { mr[m][j] = -1e30f; lr[m][j] = 0.f; }
#pragma unroll
    for (int m = 0; m < 2; ++m)
#pragma unroll
        for (int n = 0; n < 4; ++n) Oa[m][n] = (f32x4){0.f, 0.f, 0.f, 0.f};

    const int sr = tid >> 2;          // stage row 0..63
    const int sc = (tid & 3) * 16;    // stage col base (16 elems)

    for (int kt = 0; kt < 16; ++kt) {
        __syncthreads();
        // ---- stage K (row-major, XOR swz) and V^T (d-major, XOR swz) ----
        const short* kr = qkvs + (size_t)(b * 1024 + kt * 64 + sr) * 1536 + 512 + h * 64 + sc;
        short8 k0 = *(const short8*)kr;
        short8 k1 = *(const short8*)(kr + 8);
        short8 v0 = *(const short8*)(kr + 512);
        short8 v1 = *(const short8*)(kr + 520);
        const int swr = (sr & 7) << 4;
        *(short8*)&Ks[(sr * 128 + ((sc * 2) ^ swr)) >> 1] = k0;
        *(short8*)&Ks[(sr * 128 + ((sc * 2 + 16) ^ swr)) >> 1] = k1;
#pragma unroll
        for (int e = 0; e < 8; ++e) {
            const int d = sc + e;
            Vt[(d * 128 + ((sr * 2) ^ ((d & 7) << 4))) >> 1] = v0[e];
        }
#pragma unroll
        for (int e = 0; e < 8; ++e) {
            const int d = sc + 8 + e;
            Vt[(d * 128 + ((sr * 2) ^ ((d & 7) << 4))) >> 1] = v1[e];
        }
        __syncthreads();

        // ---- K / V^T B-fragments ----
        short8 kf[4][2], vf[4][2];
#pragma unroll
        for (int n = 0; n < 4; ++n) {
            const int r  = n * 16 + li;
            const int sw = (r & 7) << 4;
#pragma unroll
            for (int ks = 0; ks < 2; ++ks) {
                const int cb = ks * 64 + g * 16;
                kf[n][ks] = *(const short8*)&Ks[(r * 128 + (cb ^ sw)) >> 1];
                vf[n][ks] = *(const short8*)&Vt[(r * 128 + (cb ^ sw)) >> 1];
            }
        }

        // ---- S = Q K^T ----
        f32x4 s[2][4];
#pragma unroll
        for (int m = 0; m < 2; ++m)
#pragma unroll
            for (int n = 0; n < 4; ++n) s[m][n] = (f32x4){0.f, 0.f, 0.f, 0.f};
#pragma unroll
        for (int m = 0; m < 2; ++m)
#pragma unroll
            for (int n = 0; n < 4; ++n)
#pragma unroll
                for (int ks = 0; ks < 2; ++ks)
                    s[m][n] = __builtin_amdgcn_mfma_f32_16x16x32_bf16(qf[m][ks], kf[n][ks], s[m][n], 0, 0, 0);

        // ---- online softmax (row = m*16 + g*4 + j, col = n*16 + li) ----
#pragma unroll
        for (int m = 0; m < 2; ++m) {
            float cc[4];
#pragma unroll
            for (int j = 0; j < 4; ++j) {
                float rm = fmaxf(fmaxf(s[m][0][j], s[m][1][j]), fmaxf(s[m][2][j], s[m][3][j]));
                rm *= 0.125f;
#pragma unroll
                for (int d = 1; d < 16; d <<= 1) rm = fmaxf(rm, __shfl_xor(rm, d, 64));
                const float mn = fmaxf(mr[m][j], rm);
                cc[j] = __expf(mr[m][j] - mn);
                mr[m][j] = mn;
            }
            float rs[4] = {0.f, 0.f, 0.f, 0.f};
#pragma unroll
            for (int n = 0; n < 4; ++n)
#pragma unroll
                for (int j = 0; j < 4; ++j) {
                    const float pv = __expf(s[m][n][j] * 0.125f - mr[m][j]);
                    rs[j] += pv;
                    const int r  = m * 16 + g * 4 + j;
                    const int cb = (n * 16 + li) * 2;
                    Pl[(w * 4096 + r * 128 + (cb ^ ((r & 7) << 4))) >> 1] = (short)f2bu(pv);
                }
#pragma unroll
            for (int j = 0; j < 4; ++j) {
#pragma unroll
                for (int d = 1; d < 16; d <<= 1) rs[j] += __shfl_xor(rs[j], d, 64);
                lr[m][j] = lr[m][j] * cc[j] + rs[j];
#pragma unroll
                for (int n = 0; n < 4; ++n) Oa[m][n][j] *= cc[j];
            }
        }
        __syncthreads();

        // ---- P A-fragments + PV ----
        short8 pa[2][2];
#pragma unroll
        for (int m = 0; m < 2; ++m) {
            const int r  = m * 16 + li;
            const int sw = (r & 7) << 4;
#pragma unroll
            for (int ks = 0; ks < 2; ++ks) {
                const int cb = ks * 64 + g * 16;
                pa[m][ks] = *(const short8*)&Pl[(w * 4096 + r * 128 + (cb ^ sw)) >> 1];
            }
        }
#pragma unroll
        for (int m = 0; m < 2; ++m)
#pragma unroll
            for (int n = 0; n < 4; ++n)
#pragma unroll
                for (int ks = 0; ks < 2; ++ks)
                    Oa[m][n] = __builtin_amdgcn_mfma_f32_16x16x32_bf16(pa[m][ks], vf[n][ks], Oa[m][n], 0, 0, 0);
    }

    // ---- normalize + write ----
#pragma unroll
    for (int m = 0; m < 2; ++m)
#pragma unroll
        for (int j = 0; j < 4; ++j) {
            const float inv = 1.f / lr[m][j];
            const size_t row = (size_t)(b * 1024 + qb + m * 16 + g * 4 + j);
#pragma unroll
            for (int n = 0; n < 4; ++n)
                o[row * 512 + h * 64 + n * 16 + li] = __float2bfloat16(Oa[m][n][j] * inv);
        }
}

// ---------------------------------------------------------------------------

extern "C" void kernel_launch(void* const* d_in, const int* in_sizes, int n_in,
                              void* d_out, int out_size, void* d_ws, size_t ws_size,
                              hipStream_t stream)
{
    const float* x       = (const float*)d_in[0];
    const float* wts     = (const float*)d_in[1];
    const float* cw1     = (const float*)d_in[2];
    const float* cb1     = (const float*)d_in[3];
    const float* bn1     = (const float*)d_in[4];
    const float* cw2     = (const float*)d_in[5];
    const float* cb2     = (const float*)d_in[6];
    const float* bn2     = (const float*)d_in[7];
    const float* cw3     = (const float*)d_in[8];
    const float* cb3     = (const float*)d_in[9];
    const float* bn3     = (const float*)d_in[10];
    const float* cw4     = (const float*)d_in[11];
    const float* cb4     = (const float*)d_in[12];
    const float* bn4     = (const float*)d_in[13];
    const float* cw5     = (const float*)d_in[14];
    const float* tcw_in  = (const float*)d_in[15];
    const float* tcb_in  = (const float*)d_in[16];
    const float* t_in_w  = (const float*)d_in[17];
    const float* t_in_b  = (const float*)d_in[18];
    const float* t_out_w = (const float*)d_in[19];
    const float* t_out_b = (const float*)d_in[20];
    const float* ln1_g   = (const float*)d_in[21];
    const float* ln1_b   = (const float*)d_in[22];
    const float* ff_w1   = (const float*)d_in[23];
    const float* ff_b1   = (const float*)d_in[24];
    const float* ff_w2   = (const float*)d_in[25];
    const float* ff_b2   = (const float*)d_in[26];
    const float* ln2_g   = (const float*)d_in[27];
    const float* ln2_b   = (const float*)d_in[28];
    const float* tcw_out = (const float*)d_in[29];
    const float* tcb_out = (const float*)d_in[30];
    const float* cw6     = (const float*)d_in[31];
    const float* bn6     = (const float*)d_in[32];
    const float* bw1     = (const float*)d_in[33];
    const float* bb1     = (const float*)d_in[34];
    const float* bw2     = (const float*)d_in[35];
    const float* bb2     = (const float*)d_in[36];
    const float* bw3     = (const float*)d_in[37];
    const float* bb3     = (const float*)d_in[38];
    float* out = (float*)d_out;

    const size_t MBy = 1048576;
    char* ws = (char*)d_ws;
    __hip_bfloat16* xb    = (__hip_bfloat16*)(ws);                 // 32MB, later wtf/h7
    __hip_bfloat16* bigqb = (__hip_bfloat16*)(ws + 32 * MBy);      // 24MB qkv bf16
    __hip_bfloat16* wte   = (__hip_bfloat16*)(ws + 32 * MBy);      // early weights (alias bigqb)
    __hip_bfloat16* wtf   = (__hip_bfloat16*)(ws);                 // transformer weights (alias xb)
    float*          h7    = (float*)(ws);                          // 64MB (alias xb+bigqb)
    __hip_bfloat16* wt6   = (__hip_bfloat16*)(ws + 64 * MBy);      // 12MB cw6 weights
    __hip_bfloat16* bigb  = (__hip_bfloat16*)(ws + 80 * MBy);      // 32MB ff hidden bf16
    __hip_bfloat16* h7b   = (__hip_bfloat16*)(ws + 80 * MBy);      // alias bigb (after ff done)
    float*          outd  = (float*)(ws + 112 * MBy);              // 16MB
    __hip_bfloat16* outdb = (__hip_bfloat16*)(ws + 128 * MBy);     // 8MB
    float*          tmp   = (float*)(ws + 136 * MBy);              // 16MB fp32 LN input
    __hip_bfloat16* zb    = (__hip_bfloat16*)(ws + 136 * MBy);     // 4KB zero row (alias tmp head)
    __hip_bfloat16* wtb1  = (__hip_bfloat16*)(ws + 137 * MBy);
    __hip_bfloat16* wtb2  = (__hip_bfloat16*)(ws + 140 * MBy);
    __hip_bfloat16* wtb3  = (__hip_bfloat16*)(ws + 144 * MBy);
    __hip_bfloat16* tmpb  = (__hip_bfloat16*)(ws + 152 * MBy);     // 8MB conv5 out
    float*          xtf   = (float*)(ws + 160 * MBy);              // 16MB
    __hip_bfloat16* xtfb  = (__hip_bfloat16*)(ws + 176 * MBy);     // 8MB
    __hip_bfloat16* atnb  = (__hip_bfloat16*)(ws + 184 * MBy);     // 8MB

    const int M = 8192;
    dim3 blk(256);

    auto wtrans = [&](const float* src, __hip_bfloat16* dst, int N, int K, int taps) {
        int total = N * K * taps;
        int g = (total + 255) / 256; if (g > 4096) g = 4096;
        wtrans_kernel<<<dim3(g), blk, 0, stream>>>(src, dst, N, K, taps);
    };

    auto mg = [&](int bm, int epi, const __hip_bfloat16* A1, const __hip_bfloat16* A2,
                  int split, int lda1, int lda2,
                  const __hip_bfloat16* Bw, const float* bias,
                  float* Cf, __hip_bfloat16* Cb, int ldc, int N, int K,
                  int ntaps, int p0, int p1, int p2, int p3, int p4,
                  const float* bnp, const float* wtp, int wti, int accum,
                  const float* r1, int ldr, const float* r2) {
        dim3 grid(M / bm, N / 128);
#define LAU(BMV, EPIV) mgemm<BMV, EPIV><<<grid, blk, 0, stream>>>(A1, A2, split, lda1, lda2, \
        Bw, bias, Cf, Cb, ldc, N, K, 1024, ntaps, p0, p1, p2, p3, p4, bnp, wtp, wti, accum, r1, ldr, r2, zb)
        if (bm == 64) {
            switch (epi) { case 0: LAU(64, 0); break; case 1: LAU(64, 1); break;
                           case 2: LAU(64, 2); break; default: LAU(64, 3); }
        } else {
            switch (epi) { case 0: LAU(128, 0); break; case 1: LAU(128, 1); break;
                           case 2: LAU(128, 2); break; default: LAU(128, 3); }
        }
#undef LAU
    };

    // zero scratch row for conv-boundary masking
    hipMemsetAsync(zb, 0, 4096, stream);
    // x -> bf16
    cast_kernel<<<dim3(2048), blk, 0, stream>>>(x, (unsigned short*)xb, M * 2048 / 8);

    // --- multi-dilation branches ---
    wtrans(cw1, wte, 512, 2048, 3);
    mg(64, 2, xb, xb, 4096, 2048, 2048, wte, cb1, outd, nullptr, 512, 512, 2048,
       3, -1, 0, 1, 0, 0, bn1, wts, 0, 0, nullptr, 0, nullptr);
    wtrans(cw2, wte, 512, 2048, 3);
    mg(64, 2, xb, xb, 4096, 2048, 2048, wte, cb2, outd, nullptr, 512, 512, 2048,
       3, -2, 0, 2, 0, 0, bn2, wts, 1, 1, nullptr, 0, nullptr);
    wtrans(cw3, wte, 512, 2048, 3);
    mg(64, 2, xb, xb, 4096, 2048, 2048, wte, cb3, outd, nullptr, 512, 512, 2048,
       3, -4, 0, 4, 0, 0, bn3, wts, 2, 1, nullptr, 0, nullptr);
    wtrans(cw4, wte, 512, 2048, 5);
    mg(64, 2, xb, xb, 4096, 2048, 2048, wte, cb4, outd, outdb, 512, 512, 2048,
       5, -8, -4, 0, 4, 8, bn4, wts, 3, 1, nullptr, 0, nullptr);

    // --- conv5 (relu, no bias) -> tmpb ---
    wtrans(cw5, wte, 512, 2048, 1);
    mg(64, 1, xb, xb, 4096, 2048, 2048, wte, nullptr, nullptr, tmpb, 512, 512, 2048,
       1, 0, 0, 0, 0, 0, nullptr, nullptr, 0, 0, nullptr, 0, nullptr);

    // --- tcw_in -> xtf (+xtfb) ---   (xb region now dead -> wtf)
    wtrans(tcw_in, wtf, 512, 512, 1);
    mg(64, 0, tmpb, tmpb, 4096, 512, 512, wtf, tcb_in, xtf, xtfb, 512, 512, 512,
       1, 0, 0, 0, 0, 0, nullptr, nullptr, 0, 0, nullptr, 0, nullptr);

    // --- transformer layers ---
    for (int l = 0; l < 2; ++l) {
        wtrans(t_in_w + (size_t)l * 1536 * 512, wtf, 1536, 512, 1);
        mg(128, 0, xtfb, xtfb, 4096, 512, 512, wtf, t_in_b + l * 1536, nullptr, bigqb, 1536,
           1536, 512, 1, 0, 0, 0, 0, 0, nullptr, nullptr, 0, 0, nullptr, 0, nullptr);
        mattn<<<dim3(64, 8), blk, 0, stream>>>(bigqb, atnb);
        wtrans(t_out_w + (size_t)l * 512 * 512, wtf, 512, 512, 1);
        mg(64, 0, atnb, atnb, 4096, 512, 512, wtf, t_out_b + l * 512, tmp, nullptr, 512,
           512, 512, 1, 0, 0, 0, 0, 0, nullptr, nullptr, 0, 0, nullptr, 0, nullptr);
        ln_kernel<<<dim3(M / 4), blk, 0, stream>>>(xtf, tmp, ln1_g + l * 512, ln1_b + l * 512, xtfb, M);
        wtrans(ff_w1 + (size_t)l * 2048 * 512, wtf, 2048, 512, 1);
        mg(128, 1, xtfb, xtfb, 4096, 512, 512, wtf, ff_b1 + l * 2048, nullptr, bigb, 2048,
           2048, 512, 1, 0, 0, 0, 0, 0, nullptr, nullptr, 0, 0, nullptr, 0, nullptr);
        wtrans(ff_w2 + (size_t)l * 512 * 2048, wtf, 512, 2048, 1);
        mg(64, 0, bigb, bigb, 4096, 2048, 2048, wtf, ff_b2 + l * 512, tmp, nullptr, 512,
           512, 2048, 1, 0, 0, 0, 0, 0, nullptr, nullptr, 0, 0, nullptr, 0, nullptr);
        ln_kernel<<<dim3(M / 4), blk, 0, stream>>>(xtf, tmp, ln2_g + l * 512, ln2_b + l * 512, xtfb, M);
    }

    // --- tcw_out -> atnb (bf16 only) ---
    wtrans(tcw_out, wtf, 512, 512, 1);
    mg(64, 0, xtfb, xtfb, 4096, 512, 512, wtf, tcb_out, nullptr, atnb, 512, 512, 512,
       1, 0, 0, 0, 0, 0, nullptr, nullptr, 0, 0, nullptr, 0, nullptr);

    // --- cw6: concat(outdb, atnb) k=3 -> BN6 -> h7 (fp32 + bf16) ---
    hipMemsetAsync(zb, 0, 4096, stream);   // tmp region was clobbered; re-zero mask row
    wtrans(cw6, wt6, 2048, 1024, 3);
    mg(128, 2, outdb, atnb, 512, 512, 512, wt6, nullptr, h7, h7b, 2048, 2048, 1024,
       3, -1, 0, 1, 0, 0, bn6, nullptr, 0, 0, nullptr, 0, nullptr);

    // --- bottleneck ---
    wtrans(bw1, wtb1, 512, 2048, 1);
    mg(64, 1, h7b, h7b, 4096, 2048, 2048, wtb1, bb1, nullptr, outdb, 512, 512, 2048,
       1, 0, 0, 0, 0, 0, nullptr, nullptr, 0, 0, nullptr, 0, nullptr);
    wtrans(bw2, wtb2, 512, 512, 3);
    mg(64, 1, outdb, outdb, 4096, 512, 512, wtb2, bb2, nullptr, tmpb, 512, 512, 512,
       3, -1, 0, 1, 0, 0, nullptr, nullptr, 0, 0, nullptr, 0, nullptr);
    wtrans(bw3, wtb3, 2048, 512, 1);
    mg(128, 3, tmpb, tmpb, 4096, 512, 512, wtb3, bb3, out, nullptr, 2048, 2048, 512,
       1, 0, 0, 0, 0, 0, nullptr, nullptr, 0, 0, h7, 2048, x);

    (void)in_sizes; (void)n_in; (void)out_size; (void)ws_size;
}